// Round 3
// baseline (436.859 us; speedup 1.0000x reference)
//
#include <hip/hip_runtime.h>
#include <math.h>

#define BATCH 64
#define LSEQ  16384
#define DIM   64
#define KSEL  256
#define CHUNK 2048            // rows per stage-1 block
#define NCHUNK (LSEQ / CHUNK) // 8 stage-1 blocks per batch
#define NCAND (NCHUNK * KSEL) // 2048 candidates per batch

// ---------------------------------------------------------------------------
// Kernel 1: sims[b][l] = g * dot(q,k) / (|q||k|) in FP64 (ordering must match
// the float64 numpy reference exactly; fp32 flips ~10 adjacent top-k pairs).
// 16 lanes per key row, each lane one float4 -> 1 KB contiguous wave loads.
// Proven bit-exact in round 2 (absmax 0.0).
// ---------------------------------------------------------------------------
__global__ __launch_bounds__(256) void sim_kernel(
    const float* __restrict__ q,
    const float* __restrict__ keys,
    const float* __restrict__ gp,
    double* __restrict__ sims)
{
    const int b     = blockIdx.x >> 6;
    const int chunk = blockIdx.x & 63;
    const int t  = threadIdx.x;
    const int j  = t & 15;
    const int rl = t >> 4;

    const float4* q4 = reinterpret_cast<const float4*>(q) + b * 16;
    float4 qv = q4[j];
    const double qx = qv.x, qy = qv.y, qz = qv.z, qw = qv.w;
    double qss = qx*qx + qy*qy + qz*qz + qw*qw;
    #pragma unroll
    for (int m = 1; m < 16; m <<= 1) qss += __shfl_xor(qss, m);
    const double scale = (double)gp[0] / sqrt(qss);

    __shared__ double local[256];
    const float4* k4 = reinterpret_cast<const float4*>(keys) + (size_t)b * LSEQ * 16;
    const int row_base = chunk * 256;

    for (int it = 0; it < 16; ++it) {
        const int row = row_base + it * 16 + rl;
        float4 kv = k4[row * 16 + j];
        const double kx = kv.x, ky = kv.y, kz = kv.z, kw = kv.w;
        double dot = qx*kx + qy*ky + qz*kz + qw*kw;
        double kss = kx*kx + ky*ky + kz*kz + kw*kw;
        #pragma unroll
        for (int m = 1; m < 16; m <<= 1) {
            dot += __shfl_xor(dot, m);
            kss += __shfl_xor(kss, m);
        }
        if (j == 0) local[it * 16 + rl] = scale * dot / sqrt(kss);
    }
    __syncthreads();
    sims[(size_t)b * LSEQ + row_base + t] = local[t];
}

__device__ __forceinline__ unsigned long long f64_sortable(double v) {
    unsigned long long u = (unsigned long long)__double_as_longlong(v);
    return (u >> 63) ? ~u : (u | 0x8000000000000000ull);
}
__device__ __forceinline__ double sortable_f64(unsigned long long k) {
    unsigned long long u = (k & 0x8000000000000000ull)
                         ? (k ^ 0x8000000000000000ull) : ~k;
    return __longlong_as_double((long long)u);
}

// ---------------------------------------------------------------------------
// Stage 1: per 2048-row chunk, local top-256 superset via bitonic sort of
// packed u64 items (hi32 of sortable key | ~local idx). No atomics, no big
// register arrays. Emits (full sortable key, in-batch idx) candidates.
// ---------------------------------------------------------------------------
__global__ __launch_bounds__(256) void stage1_kernel(
    const double* __restrict__ sims,
    ulonglong2* __restrict__ cand)
{
    const int b     = blockIdx.x >> 3;
    const int chunk = blockIdx.x & 7;
    const int t     = threadIdx.x;
    const int base  = chunk * CHUNK;
    const double* s = sims + (size_t)b * LSEQ + base;

    __shared__ unsigned long long items[CHUNK];  // 16 KB
    __shared__ unsigned lo[CHUNK];               //  8 KB

    #pragma unroll
    for (int it = 0; it < CHUNK / 256; ++it) {
        int lidx = it * 256 + t;
        unsigned long long key = f64_sortable(s[lidx]);
        items[lidx] = (key & 0xFFFFFFFF00000000ull) |
                      (unsigned long long)(0xFFFFFFFFu - (unsigned)lidx);
        lo[lidx] = (unsigned)key;
    }

    // Bitonic sort 2048 u64 ascending.
    for (int size = 2; size <= CHUNK; size <<= 1) {
        for (int stride = size >> 1; stride > 0; stride >>= 1) {
            __syncthreads();
            #pragma unroll
            for (int r = 0; r < CHUNK / 512; ++r) {
                int tt = r * 256 + t;
                int i  = ((tt & ~(stride - 1)) << 1) | (tt & (stride - 1));
                int jj = i + stride;
                bool up = ((i & size) == 0);
                unsigned long long a = items[i], c = items[jj];
                if ((a > c) == up) { items[i] = c; items[jj] = a; }
            }
        }
    }
    __syncthreads();

    // Emit top 256 (largest items) with full 64-bit keys.
    unsigned long long item = items[CHUNK - 1 - t];
    unsigned lidx = 0xFFFFFFFFu - (unsigned)item;
    unsigned long long fullkey = (item & 0xFFFFFFFF00000000ull) |
                                 (unsigned long long)lo[lidx];
    cand[((size_t)b * NCHUNK + chunk) * KSEL + t] =
        make_ulonglong2(fullkey, (unsigned long long)(base + lidx));
}

// ---------------------------------------------------------------------------
// Stage 2: exact sort of 2048 candidates per batch on (key desc, idx asc),
// take top-256, fp64 softmax, gather values. One block per batch.
// ---------------------------------------------------------------------------
__global__ __launch_bounds__(256) void stage2_kernel(
    const ulonglong2* __restrict__ cand,
    const float* __restrict__ values,
    float* __restrict__ out)
{
    const int b = blockIdx.x;
    const int t = threadIdx.x;
    const ulonglong2* c = cand + (size_t)b * NCAND;

    __shared__ ulonglong2 arr[NCAND];  // 32 KB

    #pragma unroll
    for (int it = 0; it < NCAND / 256; ++it)
        arr[it * 256 + t] = c[it * 256 + t];

    // Bitonic sort ascending where "greater" = (key>, or key== && idx<).
    for (int size = 2; size <= NCAND; size <<= 1) {
        for (int stride = size >> 1; stride > 0; stride >>= 1) {
            __syncthreads();
            #pragma unroll
            for (int r = 0; r < NCAND / 512; ++r) {
                int tt = r * 256 + t;
                int i  = ((tt & ~(stride - 1)) << 1) | (tt & (stride - 1));
                int jj = i + stride;
                bool up = ((i & size) == 0);
                ulonglong2 a = arr[i], cc = arr[jj];
                bool agt = (a.x > cc.x) || (a.x == cc.x && a.y < cc.y);
                if (agt == up) { arr[i] = cc; arr[jj] = a; }
            }
        }
    }
    __syncthreads();

    // t-th largest: desc key, ties -> ascending idx (jax.lax.top_k order).
    ulonglong2 v = arr[NCAND - 1 - t];
    unsigned idx = (unsigned)v.y;
    double sv = sortable_f64(v.x);
    double fm = sortable_f64(arr[NCAND - 1].x);   // max sim

    double e = exp(sv - fm);
    double esum = e;
    #pragma unroll
    for (int m = 1; m < 64; m <<= 1) esum += __shfl_xor(esum, m);
    __shared__ double wsum[4];
    if ((t & 63) == 0) wsum[t >> 6] = esum;
    __syncthreads();
    const double tot = wsum[0] + wsum[1] + wsum[2] + wsum[3];

    out[b * KSEL + t]                = values[(size_t)b * LSEQ + idx];
    out[BATCH * KSEL + b * KSEL + t] = (float)(e / tot);
}

// ---------------------------------------------------------------------------
extern "C" void kernel_launch(void* const* d_in, const int* in_sizes, int n_in,
                              void* d_out, int out_size, void* d_ws, size_t ws_size,
                              hipStream_t stream)
{
    const float* q      = (const float*)d_in[0];
    const float* keys   = (const float*)d_in[1];
    const float* values = (const float*)d_in[2];
    const float* g      = (const float*)d_in[3];
    float* out   = (float*)d_out;

    double* sims     = (double*)d_ws;                            // 8 MB
    ulonglong2* cand = (ulonglong2*)((char*)d_ws + (size_t)BATCH * LSEQ * 8); // 2 MB

    sim_kernel<<<dim3(BATCH * (LSEQ / 256)), dim3(256), 0, stream>>>(q, keys, g, sims);
    stage1_kernel<<<dim3(BATCH * NCHUNK), dim3(256), 0, stream>>>(sims, cand);
    stage2_kernel<<<dim3(BATCH), dim3(256), 0, stream>>>(cand, values, out);
}

// Round 4
// 419.518 us; speedup vs baseline: 1.0413x; 1.0413x over previous
//
#include <hip/hip_runtime.h>
#include <math.h>

#define BATCH 64
#define LSEQ  16384
#define DIM   64
#define KSEL  256
#define CHUNK 1024            // rows per stage-1 block
#define NRUNS (CHUNK / 256)   // 4 runs per chunk
#define NCHUNK (LSEQ / CHUNK) // 16 stage-1 blocks per batch
#define NCAND (NCHUNK * KSEL) // 4096 candidates per batch

// ---------------------------------------------------------------------------
// Kernel 1: sims[b][l] = g * dot(q,k)/(|q||k|) in FP64 (bit-exact vs the
// float64 numpy reference; proven absmax 0.0 in rounds 2-3). 16 lanes per
// key row, each lane one float4 -> 1 KB contiguous wave loads. HBM-bound.
// ---------------------------------------------------------------------------
__global__ __launch_bounds__(256) void sim_kernel(
    const float* __restrict__ q,
    const float* __restrict__ keys,
    const float* __restrict__ gp,
    double* __restrict__ sims)
{
    const int b     = blockIdx.x >> 6;
    const int chunk = blockIdx.x & 63;
    const int t  = threadIdx.x;
    const int j  = t & 15;
    const int rl = t >> 4;

    const float4* q4 = reinterpret_cast<const float4*>(q) + b * 16;
    float4 qv = q4[j];
    const double qx = qv.x, qy = qv.y, qz = qv.z, qw = qv.w;
    double qss = qx*qx + qy*qy + qz*qz + qw*qw;
    #pragma unroll
    for (int m = 1; m < 16; m <<= 1) qss += __shfl_xor(qss, m);
    const double scale = (double)gp[0] / sqrt(qss);

    __shared__ double local[256];
    const float4* k4 = reinterpret_cast<const float4*>(keys) + (size_t)b * LSEQ * 16;
    const int row_base = chunk * 256;

    for (int it = 0; it < 16; ++it) {
        const int row = row_base + it * 16 + rl;
        float4 kv = k4[row * 16 + j];
        const double kx = kv.x, ky = kv.y, kz = kv.z, kw = kv.w;
        double dot = qx*kx + qy*ky + qz*kz + qw*kw;
        double kss = kx*kx + ky*ky + kz*kz + kw*kw;
        #pragma unroll
        for (int m = 1; m < 16; m <<= 1) {
            dot += __shfl_xor(dot, m);
            kss += __shfl_xor(kss, m);
        }
        if (j == 0) local[it * 16 + rl] = scale * dot / sqrt(kss);
    }
    __syncthreads();
    sims[(size_t)b * LSEQ + row_base + t] = local[t];
}

__device__ __forceinline__ unsigned long long f64_sortable(double v) {
    unsigned long long u = (unsigned long long)__double_as_longlong(v);
    return (u >> 63) ? ~u : (u | 0x8000000000000000ull);
}
__device__ __forceinline__ double sortable_f64(unsigned long long k) {
    unsigned long long u = (k & 0x8000000000000000ull)
                         ? (k ^ 0x8000000000000000ull) : ~k;
    return __longlong_as_double((long long)u);
}
// rank order: higher key first; equal key -> lower idx first (jax.lax.top_k)
__device__ __forceinline__ bool rank_gt(ulonglong2 a, ulonglong2 b) {
    return (a.x > b.x) || (a.x == b.x && a.y < b.y);
}

// ---------------------------------------------------------------------------
// Stage 1: per 1024-row chunk, top-256 via bitonic top-k tournament:
// sort 256-runs asc, then merge pairs keeping top-256 (max(A[i],B[255-i]) +
// 8-stage cleanup). Items pack 53 key bits | 11-bit inverted local idx
// (tie-exact to 2^-41 rel). Final 256 re-sorted exactly on (full key, idx).
// ---------------------------------------------------------------------------
__global__ __launch_bounds__(256) void stage1_kernel(
    const double* __restrict__ sims,
    ulonglong2* __restrict__ cand)
{
    const int b     = blockIdx.x >> 4;
    const int chunk = blockIdx.x & 15;
    const int t     = threadIdx.x;
    const int base  = chunk * CHUNK;
    const double* s = sims + (size_t)b * LSEQ + base;

    __shared__ unsigned long long items[CHUNK];   // 8 KB
    __shared__ ulonglong2 cand2[KSEL];            // 4 KB

    #pragma unroll
    for (int r = 0; r < CHUNK / 256; ++r) {
        int lidx = r * 256 + t;
        unsigned long long key = f64_sortable(s[lidx]);
        items[lidx] = (key & ~0x7FFull) | (unsigned long long)(0x7FF - lidx);
    }

    // Phase A: sort each 256-segment ascending (force up at size=256).
    for (int size = 2; size <= 256; size <<= 1) {
        for (int stride = size >> 1; stride > 0; stride >>= 1) {
            __syncthreads();
            #pragma unroll
            for (int r = 0; r < CHUNK / 512; ++r) {
                int tt = r * 256 + t;
                int i = ((tt & ~(stride - 1)) << 1) | (tt & (stride - 1));
                bool up = (size == 256) ? true : ((i & size) == 0);
                unsigned long long a = items[i], c = items[i + stride];
                if ((a > c) == up) { items[i] = c; items[i + stride] = a; }
            }
        }
    }

    // Phase B: tournament 4 -> 2 -> 1 runs.
    for (int nr = NRUNS; nr > 1; nr >>= 1) {
        const int nout = (nr >> 1) * 256;
        __syncthreads();
        unsigned long long keep[2];
        #pragma unroll
        for (int c = 0; c < 2; ++c) {
            int lane = c * 256 + t;
            if (lane < nout) {
                int j = lane >> 8, i = lane & 255;
                unsigned long long a = items[(2 * j) * 256 + i];
                unsigned long long bb = items[(2 * j) * 256 + 511 - i];
                keep[c] = a > bb ? a : bb;
            }
        }
        __syncthreads();
        #pragma unroll
        for (int c = 0; c < 2; ++c) {
            int lane = c * 256 + t;
            if (lane < nout) items[lane] = keep[c];
        }
        // cleanup: each 256-run is bitonic -> 8-stage merge to asc.
        for (int stride = 128; stride > 0; stride >>= 1) {
            __syncthreads();
            #pragma unroll
            for (int c = 0; c < 1; ++c) {
                int lane = t;
                if (lane < (nout >> 1)) {
                    int seg = lane >> 7, loc = lane & 127;
                    int i = seg * 256 + (((loc & ~(stride - 1)) << 1) | (loc & (stride - 1)));
                    unsigned long long a = items[i], cc = items[i + stride];
                    if (a > cc) { items[i] = cc; items[i + stride] = a; }
                }
            }
        }
    }
    __syncthreads();

    // Recover full keys; exact sort of 256 on (key64, idx) asc-by-rank.
    {
        unsigned long long item = items[t];
        int lidx = 0x7FF - (int)(item & 0x7FF);
        cand2[t] = make_ulonglong2(f64_sortable(s[lidx]),
                                   (unsigned long long)(base + lidx));
    }
    for (int size = 2; size <= 256; size <<= 1) {
        for (int stride = size >> 1; stride > 0; stride >>= 1) {
            __syncthreads();
            if (t < 128) {
                int i = ((t & ~(stride - 1)) << 1) | (t & (stride - 1));
                bool up = ((i & size) == 0);
                ulonglong2 a = cand2[i], c = cand2[i + stride];
                if (rank_gt(a, c) == up) { cand2[i] = c; cand2[i + stride] = a; }
            }
        }
    }
    __syncthreads();
    cand[((size_t)(b * NCHUNK + chunk)) * KSEL + t] = cand2[t];
}

// ---------------------------------------------------------------------------
// Stage 2: 16 exactly-sorted runs/batch -> tournament merge to exact top-256
// (desc, ties -> lowest idx), fp64 softmax, gather. One block per batch.
// ---------------------------------------------------------------------------
__global__ __launch_bounds__(256) void stage2_kernel(
    const ulonglong2* __restrict__ cand,
    const float* __restrict__ values,
    float* __restrict__ out)
{
    const int b = blockIdx.x;
    const int t = threadIdx.x;
    __shared__ ulonglong2 arr[NCAND];   // 64 KB

    #pragma unroll
    for (int r = 0; r < NCAND / 256; ++r)
        arr[r * 256 + t] = cand[(size_t)b * NCAND + r * 256 + t];

    for (int nr = NCHUNK; nr > 1; nr >>= 1) {
        const int nout = (nr >> 1) * 256;
        __syncthreads();
        ulonglong2 keep[8];
        #pragma unroll
        for (int c = 0; c < 8; ++c) {
            int lane = c * 256 + t;
            if (lane < nout) {
                int j = lane >> 8, i = lane & 255;
                ulonglong2 a  = arr[(2 * j) * 256 + i];
                ulonglong2 bb = arr[(2 * j) * 256 + 511 - i];
                keep[c] = rank_gt(a, bb) ? a : bb;
            }
        }
        __syncthreads();
        #pragma unroll
        for (int c = 0; c < 8; ++c) {
            int lane = c * 256 + t;
            if (lane < nout) arr[lane] = keep[c];
        }
        for (int stride = 128; stride > 0; stride >>= 1) {
            __syncthreads();
            #pragma unroll
            for (int c = 0; c < 4; ++c) {
                int lane = c * 256 + t;
                if (lane < (nout >> 1)) {
                    int seg = lane >> 7, loc = lane & 127;
                    int i = seg * 256 + (((loc & ~(stride - 1)) << 1) | (loc & (stride - 1)));
                    ulonglong2 a = arr[i], cc = arr[i + stride];
                    if (rank_gt(a, cc)) { arr[i] = cc; arr[i + stride] = a; }
                }
            }
        }
    }
    __syncthreads();

    // arr[0..255] asc by rank: t-th largest = arr[255-t].
    ulonglong2 v = arr[255 - t];
    unsigned idx = (unsigned)v.y;
    double sv = sortable_f64(v.x);
    double fm = sortable_f64(arr[255].x);

    double e = exp(sv - fm);
    double esum = e;
    #pragma unroll
    for (int m = 1; m < 64; m <<= 1) esum += __shfl_xor(esum, m);
    __shared__ double wsum[4];
    if ((t & 63) == 0) wsum[t >> 6] = esum;
    __syncthreads();
    const double tot = wsum[0] + wsum[1] + wsum[2] + wsum[3];

    out[b * KSEL + t]                = values[(size_t)b * LSEQ + idx];
    out[BATCH * KSEL + b * KSEL + t] = (float)(e / tot);
}

// ---------------------------------------------------------------------------
extern "C" void kernel_launch(void* const* d_in, const int* in_sizes, int n_in,
                              void* d_out, int out_size, void* d_ws, size_t ws_size,
                              hipStream_t stream)
{
    const float* q      = (const float*)d_in[0];
    const float* keys   = (const float*)d_in[1];
    const float* values = (const float*)d_in[2];
    const float* g      = (const float*)d_in[3];
    float* out   = (float*)d_out;

    double* sims     = (double*)d_ws;                                        // 8 MB
    ulonglong2* cand = (ulonglong2*)((char*)d_ws + (size_t)BATCH * LSEQ * 8); // 4 MB

    sim_kernel<<<dim3(BATCH * (LSEQ / 256)), dim3(256), 0, stream>>>(q, keys, g, sims);
    stage1_kernel<<<dim3(BATCH * NCHUNK), dim3(256), 0, stream>>>(sims, cand);
    stage2_kernel<<<dim3(BATCH), dim3(256), 0, stream>>>(cand, values, out);
}

// Round 5
// 414.201 us; speedup vs baseline: 1.0547x; 1.0128x over previous
//
#include <hip/hip_runtime.h>
#include <math.h>

#define BATCH 64
#define LSEQ  16384
#define DIM   64
#define KSEL  256
#define CHUNK 1024            // rows per fused block
#define NRUNS (CHUNK / 256)   // 4 runs per chunk
#define NCHUNK (LSEQ / CHUNK) // 16 chunks per batch
#define NCAND (NCHUNK * KSEL) // 4096 candidates per batch

__device__ __forceinline__ unsigned long long f64_sortable(double v) {
    unsigned long long u = (unsigned long long)__double_as_longlong(v);
    return (u >> 63) ? ~u : (u | 0x8000000000000000ull);
}
__device__ __forceinline__ double sortable_f64(unsigned long long k) {
    unsigned long long u = (k & 0x8000000000000000ull)
                         ? (k ^ 0x8000000000000000ull) : ~k;
    return __longlong_as_double((long long)u);
}
// rank order: higher key first; equal key -> lower idx first (jax.lax.top_k)
__device__ __forceinline__ bool rank_gt(ulonglong2 a, ulonglong2 b) {
    return (a.x > b.x) || (a.x == b.x && a.y < b.y);
}

// ---------------------------------------------------------------------------
// Fused kernel: per 1024-row chunk, compute fp64 sims (quad-per-row, Newton
// rsqrt — no fp64 div/sqrt in the hot loop) into LDS, then in-place packed
// bitonic top-256 (53-bit key | 11-bit ~lidx, proven in R4), exact re-sort
// of the 256 on (full key, idx), emit candidates. 1024 blocks x 256 thr.
// ---------------------------------------------------------------------------
__global__ __launch_bounds__(256) void sim_select_kernel(
    const float* __restrict__ q,
    const float* __restrict__ keys,
    const float* __restrict__ gp,
    ulonglong2* __restrict__ cand)
{
    const int b     = blockIdx.x >> 4;
    const int chunk = blockIdx.x & 15;
    const int t     = threadIdx.x;
    const int quad  = t >> 2;      // 0..63: row within 64-row group
    const int slot  = t & 3;       // float4 slot within a 16-float pass
    const int base  = chunk * CHUNK;

    __shared__ double sh_sims[CHUNK];             // 8 KB
    __shared__ unsigned long long items[CHUNK];   // 8 KB
    __shared__ ulonglong2 cand2[KSEL];            // 4 KB

    // ---- query: norm (once) + per-lane fragment (4 float4s, as fp64) ----
    const float4* q4 = reinterpret_cast<const float4*>(q) + b * 16;
    {
        float4 qv = q4[t & 15];
        double qs = (double)qv.x*qv.x + (double)qv.y*qv.y +
                    (double)qv.z*qv.z + (double)qv.w*qv.w;
        #pragma unroll
        for (int m = 1; m < 16; m <<= 1) qs += __shfl_xor(qs, m);
        sh_sims[0] = 0.0;  // placate compiler; overwritten below
        // stash qss in a register via broadcast; compute scale below
        items[0] = 0ull;
        // (scale computed after we read gp)
        // fallthrough
        __syncthreads();
        (void)qs;
        // recompute per-thread (cheap, once): scale
        // NOTE: kept exact fp64 div/sqrt — once per thread, not per row.
        double scale = (double)gp[0] / sqrt(qs);

        double qd[4][4];
        #pragma unroll
        for (int p = 0; p < 4; ++p) {
            float4 qf = q4[p * 4 + slot];
            qd[p][0] = qf.x; qd[p][1] = qf.y; qd[p][2] = qf.z; qd[p][3] = qf.w;
        }

        // ---- sims: 16 iters x 64 rows; quad reduces over 2 shuffle rounds ----
        const float4* k4 = reinterpret_cast<const float4*>(keys) +
                           (size_t)b * LSEQ * 16;
        for (int it = 0; it < CHUNK / 64; ++it) {
            const int lrow = it * 64 + quad;
            const int row  = base + lrow;
            double dot = 0.0, kss = 0.0;
            #pragma unroll
            for (int p = 0; p < 4; ++p) {
                float4 kv = k4[row * 16 + p * 4 + slot];
                const double kx = kv.x, ky = kv.y, kz = kv.z, kw = kv.w;
                dot += qd[p][0]*kx + qd[p][1]*ky + qd[p][2]*kz + qd[p][3]*kw;
                kss += kx*kx + ky*ky + kz*kz + kw*kw;
            }
            dot += __shfl_xor(dot, 1); dot += __shfl_xor(dot, 2);
            kss += __shfl_xor(kss, 1); kss += __shfl_xor(kss, 2);
            if (slot == 0) {
                // rsqrt: f32 seed + 3 fp64 Newton iters -> ~1ulp fp64
                double x = (double)rsqrtf((float)kss);
                #pragma unroll
                for (int nit = 0; nit < 3; ++nit)
                    x = x * (1.5 - 0.5 * kss * x * x);
                double sim = scale * dot * x;
                sh_sims[lrow] = sim;
                unsigned long long key = f64_sortable(sim);
                items[lrow] = (key & ~0x7FFull) |
                              (unsigned long long)(0x7FF - lrow);
            }
        }
    }
    __syncthreads();

    // ---- Phase A: sort each 256-segment ascending (force up at size=256) ----
    for (int size = 2; size <= 256; size <<= 1) {
        for (int stride = size >> 1; stride > 0; stride >>= 1) {
            #pragma unroll
            for (int r = 0; r < CHUNK / 512; ++r) {
                int tt = r * 256 + t;
                int i = ((tt & ~(stride - 1)) << 1) | (tt & (stride - 1));
                bool up = (size == 256) ? true : ((i & size) == 0);
                unsigned long long a = items[i], c = items[i + stride];
                if ((a > c) == up) { items[i] = c; items[i + stride] = a; }
            }
            __syncthreads();
        }
    }

    // ---- Phase B: tournament 4 -> 2 -> 1 runs, keep top-256 ----
    for (int nr = NRUNS; nr > 1; nr >>= 1) {
        const int nout = (nr >> 1) * 256;
        unsigned long long keep[2];
        #pragma unroll
        for (int c = 0; c < 2; ++c) {
            int lane = c * 256 + t;
            if (lane < nout) {
                int j = lane >> 8, i = lane & 255;
                unsigned long long a  = items[(2 * j) * 256 + i];
                unsigned long long bb = items[(2 * j) * 256 + 511 - i];
                keep[c] = a > bb ? a : bb;
            }
        }
        __syncthreads();
        #pragma unroll
        for (int c = 0; c < 2; ++c) {
            int lane = c * 256 + t;
            if (lane < nout) items[lane] = keep[c];
        }
        __syncthreads();
        for (int stride = 128; stride > 0; stride >>= 1) {
            if (t < (nout >> 1)) {
                int seg = t >> 7, loc = t & 127;
                int i = seg * 256 +
                        (((loc & ~(stride - 1)) << 1) | (loc & (stride - 1)));
                unsigned long long a = items[i], cc = items[i + stride];
                if (a > cc) { items[i] = cc; items[i + stride] = a; }
            }
            __syncthreads();
        }
    }

    // ---- recover full keys; exact sort of 256 on (key64, idx) ----
    {
        unsigned long long item = items[t];
        int lidx = 0x7FF - (int)(item & 0x7FF);
        cand2[t] = make_ulonglong2(f64_sortable(sh_sims[lidx]),
                                   (unsigned long long)(base + lidx));
    }
    __syncthreads();
    for (int size = 2; size <= 256; size <<= 1) {
        for (int stride = size >> 1; stride > 0; stride >>= 1) {
            if (t < 128) {
                int i = ((t & ~(stride - 1)) << 1) | (t & (stride - 1));
                bool up = ((i & size) == 0);
                ulonglong2 a = cand2[i], c = cand2[i + stride];
                if (rank_gt(a, c) == up) { cand2[i] = c; cand2[i + stride] = a; }
            }
            __syncthreads();
        }
    }
    cand[((size_t)(b * NCHUNK + chunk)) * KSEL + t] = cand2[t];
}

// ---------------------------------------------------------------------------
// Stage 2: 16 exactly-sorted runs/batch -> tournament merge to exact top-256
// (desc, ties -> lowest idx), fp64 softmax, gather. One block per batch.
// ---------------------------------------------------------------------------
__global__ __launch_bounds__(256) void stage2_kernel(
    const ulonglong2* __restrict__ cand,
    const float* __restrict__ values,
    float* __restrict__ out)
{
    const int b = blockIdx.x;
    const int t = threadIdx.x;
    __shared__ ulonglong2 arr[NCAND];   // 64 KB

    #pragma unroll
    for (int r = 0; r < NCAND / 256; ++r)
        arr[r * 256 + t] = cand[(size_t)b * NCAND + r * 256 + t];

    for (int nr = NCHUNK; nr > 1; nr >>= 1) {
        const int nout = (nr >> 1) * 256;
        __syncthreads();
        ulonglong2 keep[8];
        #pragma unroll
        for (int c = 0; c < 8; ++c) {
            int lane = c * 256 + t;
            if (lane < nout) {
                int j = lane >> 8, i = lane & 255;
                ulonglong2 a  = arr[(2 * j) * 256 + i];
                ulonglong2 bb = arr[(2 * j) * 256 + 511 - i];
                keep[c] = rank_gt(a, bb) ? a : bb;
            }
        }
        __syncthreads();
        #pragma unroll
        for (int c = 0; c < 8; ++c) {
            int lane = c * 256 + t;
            if (lane < nout) arr[lane] = keep[c];
        }
        for (int stride = 128; stride > 0; stride >>= 1) {
            __syncthreads();
            #pragma unroll
            for (int c = 0; c < 4; ++c) {
                int lane = c * 256 + t;
                if (lane < (nout >> 1)) {
                    int seg = lane >> 7, loc = lane & 127;
                    int i = seg * 256 +
                            (((loc & ~(stride - 1)) << 1) | (loc & (stride - 1)));
                    ulonglong2 a = arr[i], cc = arr[i + stride];
                    if (rank_gt(a, cc)) { arr[i] = cc; arr[i + stride] = a; }
                }
            }
        }
    }
    __syncthreads();

    // arr[0..255] asc by rank: t-th largest = arr[255-t].
    ulonglong2 v = arr[255 - t];
    unsigned idx = (unsigned)v.y;
    double sv = sortable_f64(v.x);
    double fm = sortable_f64(arr[255].x);

    double e = exp(sv - fm);
    double esum = e;
    #pragma unroll
    for (int m = 1; m < 64; m <<= 1) esum += __shfl_xor(esum, m);
    __shared__ double wsum[4];
    if ((t & 63) == 0) wsum[t >> 6] = esum;
    __syncthreads();
    const double tot = wsum[0] + wsum[1] + wsum[2] + wsum[3];

    out[b * KSEL + t]                = values[(size_t)b * LSEQ + idx];
    out[BATCH * KSEL + b * KSEL + t] = (float)(e / tot);
}

// ---------------------------------------------------------------------------
extern "C" void kernel_launch(void* const* d_in, const int* in_sizes, int n_in,
                              void* d_out, int out_size, void* d_ws, size_t ws_size,
                              hipStream_t stream)
{
    const float* q      = (const float*)d_in[0];
    const float* keys   = (const float*)d_in[1];
    const float* values = (const float*)d_in[2];
    const float* g      = (const float*)d_in[3];
    float* out = (float*)d_out;
    ulonglong2* cand = (ulonglong2*)d_ws;   // 4 MB

    sim_select_kernel<<<dim3(BATCH * NCHUNK), dim3(256), 0, stream>>>(q, keys, g, cand);
    stage2_kernel<<<dim3(BATCH), dim3(256), 0, stream>>>(cand, values, out);
}